// Round 1
// baseline (195.708 us; speedup 1.0000x reference)
//
#include <hip/hip_runtime.h>
#include <hip/hip_bf16.h>

typedef short short8 __attribute__((ext_vector_type(8)));   // 8 bf16 = 4 VGPRs
typedef float f32x4 __attribute__((ext_vector_type(4)));

__device__ __forceinline__ unsigned short f2bf(float f) {
  unsigned int u = __float_as_uint(f);
  u += 0x7fffu + ((u >> 16) & 1u);    // round-to-nearest-even
  return (unsigned short)(u >> 16);
}

// ---------------- cast fp32 -> bf16, 4 elems/thread ----------------
__global__ __launch_bounds__(256) void cast_bf16(const float* __restrict__ in,
                                                 unsigned short* __restrict__ out,
                                                 int n4) {
  int i = blockIdx.x * 256 + threadIdx.x;
  if (i < n4) {
    float4 v = reinterpret_cast<const float4*>(in)[i];
    ushort4 o;
    o.x = f2bf(v.x); o.y = f2bf(v.y); o.z = f2bf(v.z); o.w = f2bf(v.w);
    reinterpret_cast<ushort4*>(out)[i] = o;
  }
}

// ---------------- C[M,N] = A[M,K] @ B[N,K]^T, bf16 in/out, fp32 acc ---------
// 128x128 tile, BK=64, 256 threads = 4 waves, each wave 64x64 (4x4 mfma tiles)
__global__ __launch_bounds__(256) void gemm_bt(const unsigned short* __restrict__ A,
                                               const unsigned short* __restrict__ B,
                                               unsigned short* __restrict__ C,
                                               int M, int N, int K) {
  __shared__ short As[128][72];   // +8 pad: rows rotate 4 banks -> 2-way (free)
  __shared__ short Bs[128][72];
  const int t    = threadIdx.x;
  const int lane = t & 63;
  const int wave = t >> 6;
  const int l15  = lane & 15;
  const int quad = lane >> 4;
  const int mb = blockIdx.y * 128;
  const int nb = blockIdx.x * 128;
  const int wm = (wave & 1) * 64;
  const int wn = (wave >> 1) * 64;

  f32x4 acc[4][4];
#pragma unroll
  for (int i = 0; i < 4; i++)
#pragma unroll
    for (int j = 0; j < 4; j++) acc[i][j] = (f32x4){0.f, 0.f, 0.f, 0.f};

  const int srow  = t >> 1;        // 0..127
  const int shalf = (t & 1) * 32;  // element offset within 64-wide K slab

  for (int kb = 0; kb < K; kb += 64) {
    const short8* ga = (const short8*)(A + (size_t)(mb + srow) * K + kb + shalf);
    const short8* gb = (const short8*)(B + (size_t)(nb + srow) * K + kb + shalf);
    short8 ra0 = ga[0], ra1 = ga[1], ra2 = ga[2], ra3 = ga[3];
    short8 rb0 = gb[0], rb1 = gb[1], rb2 = gb[2], rb3 = gb[3];
    __syncthreads();                          // protect previous iter's reads
    short8* wa = (short8*)&As[srow][shalf];
    wa[0] = ra0; wa[1] = ra1; wa[2] = ra2; wa[3] = ra3;
    short8* wb = (short8*)&Bs[srow][shalf];
    wb[0] = rb0; wb[1] = rb1; wb[2] = rb2; wb[3] = rb3;
    __syncthreads();
#pragma unroll
    for (int kk = 0; kk < 64; kk += 32) {
      short8 af[4], bf[4];
#pragma unroll
      for (int mi = 0; mi < 4; mi++)
        af[mi] = *(const short8*)&As[wm + mi * 16 + l15][kk + quad * 8];
#pragma unroll
      for (int ni = 0; ni < 4; ni++)
        bf[ni] = *(const short8*)&Bs[wn + ni * 16 + l15][kk + quad * 8];
#pragma unroll
      for (int mi = 0; mi < 4; mi++)
#pragma unroll
        for (int ni = 0; ni < 4; ni++)
          acc[mi][ni] = __builtin_amdgcn_mfma_f32_16x16x32_bf16(
              af[mi], bf[ni], acc[mi][ni], 0, 0, 0);
    }
  }
  // epilogue: C/D layout col=lane&15, row=quad*4+reg
#pragma unroll
  for (int mi = 0; mi < 4; mi++)
#pragma unroll
    for (int r = 0; r < 4; r++) {
      int row = mb + wm + mi * 16 + quad * 4 + r;
#pragma unroll
      for (int ni = 0; ni < 4; ni++) {
        int col = nb + wn + ni * 16 + l15;
        C[(size_t)row * N + col] = f2bf(acc[mi][ni][r]);
      }
    }
}

// ---------------- fused QK^T + columnwise logsumexp over q + mean over a ----
// out[b,h,k] = sum_a ln( sum_q exp( (Qh[a,h,q,:]·Kh[b,h,k,:]) / 8 ) )
// grid (8 ktile64, 16 h, 8 b), 4 waves/block, each wave owns 16 k columns.
__global__ __launch_bounds__(256) void attn_lse(const unsigned short* __restrict__ Qp,
                                                const unsigned short* __restrict__ Kp,
                                                float* __restrict__ out) {
  __shared__ short qs[64][72];
  const int t    = threadIdx.x;
  const int lane = t & 63;
  const int wave = t >> 6;
  const int l15  = lane & 15;
  const int quad = lane >> 4;
  const int kt = blockIdx.x;   // k tile of 64
  const int h  = blockIdx.y;
  const int b  = blockIdx.z;
  const int kbase = kt * 64 + wave * 16;

  // K fragments held in registers for the whole kernel (d 0..31, 32..63)
  const short8* kg =
      (const short8*)(Kp + (size_t)(b * 512 + kbase + l15) * 1024 + h * 64 + quad * 8);
  short8 bk0 = kg[0];
  short8 bk1 = kg[4];   // +32 elements

  const int srow   = t >> 2;        // 0..63
  const int schunk = (t & 3) * 16;  // element offset

  float energy = 0.0f;
  for (int a = 0; a < 8; a++) {
    float csum = 0.0f;
    for (int q0 = 0; q0 < 512; q0 += 64) {
      const short8* gq =
          (const short8*)(Qp + (size_t)(a * 512 + q0 + srow) * 1024 + h * 64 + schunk);
      short8 r0 = gq[0], r1 = gq[1];
      __syncthreads();
      *(short8*)&qs[srow][schunk]     = r0;
      *(short8*)&qs[srow][schunk + 8] = r1;
      __syncthreads();
#pragma unroll
      for (int qt = 0; qt < 4; qt++) {
        short8 a0 = *(const short8*)&qs[qt * 16 + l15][quad * 8];
        short8 a1 = *(const short8*)&qs[qt * 16 + l15][32 + quad * 8];
        f32x4 acc = (f32x4){0.f, 0.f, 0.f, 0.f};
        acc = __builtin_amdgcn_mfma_f32_16x16x32_bf16(a0, bk0, acc, 0, 0, 0);
        acc = __builtin_amdgcn_mfma_f32_16x16x32_bf16(a1, bk1, acc, 0, 0, 0);
#pragma unroll
        for (int r = 0; r < 4; r++) csum += __expf(acc[r] * 0.125f);
      }
    }
    // finish q-reduction: each lane has a partial over its quad's rows
    csum += __shfl_xor(csum, 16, 64);
    csum += __shfl_xor(csum, 32, 64);
    energy += __logf(csum);
  }
  if (quad == 0) {
    out[(size_t)b * 16 * 512 + h * 512 + kbase + l15] = energy;
  }
}

extern "C" void kernel_launch(void* const* d_in, const int* in_sizes, int n_in,
                              void* d_out, int out_size, void* d_ws, size_t ws_size,
                              hipStream_t stream) {
  const float* query  = (const float*)d_in[0];  // [8,512,1024]
  const float* memory = (const float*)d_in[1];  // [8,512,1024]
  const float* wq     = (const float*)d_in[2];  // [1024,1024]
  const float* wk     = (const float*)d_in[3];  // [1024,1024]
  float* out = (float*)d_out;                   // [8,16,512]

  char* ws = (char*)d_ws;
  const size_t MB = 1024 * 1024;
  unsigned short* qb  = (unsigned short*)(ws);             // 8 MB
  unsigned short* mb_ = (unsigned short*)(ws + 8  * MB);   // 8 MB
  unsigned short* wqb = (unsigned short*)(ws + 16 * MB);   // 2 MB
  unsigned short* wkb = (unsigned short*)(ws + 18 * MB);   // 2 MB
  unsigned short* Qp  = (unsigned short*)(ws + 20 * MB);   // 8 MB
  unsigned short* Kp  = (unsigned short*)(ws + 28 * MB);   // 8 MB (total 36 MB)

  cast_bf16<<<4096, 256, 0, stream>>>(query,  qb,  1048576);
  cast_bf16<<<4096, 256, 0, stream>>>(memory, mb_, 1048576);
  cast_bf16<<<1024, 256, 0, stream>>>(wq, wqb, 262144);
  cast_bf16<<<1024, 256, 0, stream>>>(wk, wkb, 262144);
  gemm_bt<<<dim3(8, 32), 256, 0, stream>>>(qb,  wqb, Qp, 4096, 1024, 1024);
  gemm_bt<<<dim3(8, 32), 256, 0, stream>>>(mb_, wkb, Kp, 4096, 1024, 1024);
  attn_lse<<<dim3(8, 16, 8), 256, 0, stream>>>(Qp, Kp, out);
}

// Round 2
// 177.064 us; speedup vs baseline: 1.1053x; 1.1053x over previous
//
#include <hip/hip_runtime.h>
#include <hip/hip_bf16.h>

typedef short short8 __attribute__((ext_vector_type(8)));   // 8 bf16 = 4 VGPRs
typedef float f32x4 __attribute__((ext_vector_type(4)));
typedef unsigned short u16;

__device__ __forceinline__ unsigned short f2bf(float f) {
  unsigned int u = __float_as_uint(f);
  u += 0x7fffu + ((u >> 16) & 1u);    // round-to-nearest-even
  return (unsigned short)(u >> 16);
}

// async 16B global->LDS (dest = wave-uniform base + lane*16)
__device__ __forceinline__ void glds16(const void* g, void* l) {
  __builtin_amdgcn_global_load_lds(
      (const __attribute__((address_space(1))) unsigned int*)g,
      (__attribute__((address_space(3))) unsigned int*)l, 16, 0, 0);
}

// ---- fused: cast q/m -> bf16, cast wq*(1/(8 ln2)) -> bf16, cast wk, zero out ----
__global__ __launch_bounds__(256) void prep(const float4* __restrict__ q,
                                            const float4* __restrict__ m,
                                            const float4* __restrict__ wq,
                                            const float4* __restrict__ wk,
                                            ushort4* __restrict__ qb,
                                            ushort4* __restrict__ mb,
                                            ushort4* __restrict__ wqb,
                                            ushort4* __restrict__ wkb,
                                            float4* __restrict__ out0) {
  const int i = blockIdx.x * 256 + threadIdx.x;
  const float c = 0.18033688011112042f;  // 1/(8*ln2): folds SCALE and exp->exp2
  if (i < 1048576) {
    float4 v = q[i];
    ushort4 o; o.x = f2bf(v.x); o.y = f2bf(v.y); o.z = f2bf(v.z); o.w = f2bf(v.w);
    qb[i] = o;
  } else if (i < 2097152) {
    float4 v = m[i - 1048576];
    ushort4 o; o.x = f2bf(v.x); o.y = f2bf(v.y); o.z = f2bf(v.z); o.w = f2bf(v.w);
    mb[i - 1048576] = o;
  } else if (i < 2359296) {
    float4 v = wq[i - 2097152];
    ushort4 o; o.x = f2bf(v.x * c); o.y = f2bf(v.y * c); o.z = f2bf(v.z * c); o.w = f2bf(v.w * c);
    wqb[i - 2097152] = o;
  } else if (i < 2621440) {
    float4 v = wk[i - 2359296];
    ushort4 o; o.x = f2bf(v.x); o.y = f2bf(v.y); o.z = f2bf(v.z); o.w = f2bf(v.w);
    wkb[i - 2359296] = o;
  } else if (i < 2637824) {
    out0[i - 2621440] = (float4){0.f, 0.f, 0.f, 0.f};  // zero 65536-float output
  }
}

// ---- C[M,N] = A[M,1024] @ B[N,1024]^T, bf16, 128x128 tile, global_load_lds ----
// z=0: Q-proj, z=1: K-proj. LDS xor-swizzle: chunk' = chunk ^ (row&7).
__global__ __launch_bounds__(256) void gemm_bt2(const u16* __restrict__ A0,
                                                const u16* __restrict__ B0,
                                                u16* __restrict__ C0,
                                                const u16* __restrict__ A1,
                                                const u16* __restrict__ B1,
                                                u16* __restrict__ C1) {
  __shared__ u16 As[128 * 64];
  __shared__ u16 Bs[128 * 64];
  const u16* A = blockIdx.z ? A1 : A0;
  const u16* B = blockIdx.z ? B1 : B0;
  u16* C = blockIdx.z ? C1 : C0;
  const int t = threadIdx.x;
  const int lane = t & 63, wave = t >> 6;
  const int l15 = lane & 15, quad = lane >> 4;
  const int mb = blockIdx.y * 128, nb = blockIdx.x * 128;
  const int wm = (wave & 1) * 64, wn = (wave >> 1) * 64;

  const int srow = lane >> 3;                 // 0..7 row within 8-row instr group
  const int scol = ((lane & 7) ^ srow) * 8;   // swizzled source column

  f32x4 acc[4][4];
#pragma unroll
  for (int i = 0; i < 4; i++)
#pragma unroll
    for (int j = 0; j < 4; j++) acc[i][j] = (f32x4){0.f, 0.f, 0.f, 0.f};

  for (int kb = 0; kb < 1024; kb += 64) {
#pragma unroll
    for (int j = 0; j < 4; j++) {
      const int mi_ = wave * 4 + j;           // instr index 0..15
      const int row = mi_ * 8 + srow;
      glds16(A + (size_t)(mb + row) * 1024 + kb + scol, &As[mi_ * 512 + lane * 8]);
      glds16(B + (size_t)(nb + row) * 1024 + kb + scol, &Bs[mi_ * 512 + lane * 8]);
    }
    __syncthreads();   // drains vmcnt(0): LDS tiles ready
#pragma unroll
    for (int kk = 0; kk < 2; kk++) {
      const int cb = kk * 4;
      const int sw = l15 & 7;
      short8 af[4], bfr[4];
#pragma unroll
      for (int mi = 0; mi < 4; mi++)
        af[mi] = *(const short8*)&As[(wm + mi * 16 + l15) * 64 + ((cb + quad) ^ sw) * 8];
#pragma unroll
      for (int ni = 0; ni < 4; ni++)
        bfr[ni] = *(const short8*)&Bs[(wn + ni * 16 + l15) * 64 + ((cb + quad) ^ sw) * 8];
#pragma unroll
      for (int mi = 0; mi < 4; mi++)
#pragma unroll
        for (int ni = 0; ni < 4; ni++)
          acc[mi][ni] = __builtin_amdgcn_mfma_f32_16x16x32_bf16(
              af[mi], bfr[ni], acc[mi][ni], 0, 0, 0);
    }
    __syncthreads();   // all reads done before next iter's loads overwrite
  }
  // epilogue: C/D layout col=l15, row=quad*4+r (verified round 1)
#pragma unroll
  for (int mi = 0; mi < 4; mi++)
#pragma unroll
    for (int r = 0; r < 4; r++) {
      const int row = mb + wm + mi * 16 + quad * 4 + r;
      const size_t base = (size_t)row * 1024 + nb + wn;
#pragma unroll
      for (int ni = 0; ni < 4; ni++)
        C[base + ni * 16 + l15] = f2bf(acc[mi][ni][r]);
    }
}

// ---- fused QK^T + columnwise LSE, a split across blocks, atomicAdd combine ----
// Each wave owns 64 k-columns (4 mfma k-tiles, K-frags in regs). Q' is
// pre-scaled by 1/(8 ln2) so logit -> exp2f directly; out += ln(csum).
__global__ __launch_bounds__(256) void attn_lse2(const u16* __restrict__ Qp,
                                                 const u16* __restrict__ Kp,
                                                 float* __restrict__ out) {
  __shared__ u16 qs[64 * 64];
  const int t = threadIdx.x;
  const int lane = t & 63, wave = t >> 6;
  const int l15 = lane & 15, quad = lane >> 4;
  const int kt = blockIdx.x & 1, aa = blockIdx.x >> 1;
  const int h = blockIdx.y, b = blockIdx.z;
  const int kwave = kt * 256 + wave * 64;

  // K fragments for 4 k-tiles x (d-lo, d-hi), held in registers throughout
  short8 klo[4], khi[4];
#pragma unroll
  for (int tt = 0; tt < 4; tt++) {
    const short8* kg = (const short8*)(Kp + (size_t)(b * 512 + kwave + tt * 16 + l15) * 1024
                                       + h * 64 + quad * 8);
    klo[tt] = kg[0];
    khi[tt] = kg[4];   // +32 elements
  }

  const int srow = lane >> 3;
  const int scol = ((lane & 7) ^ srow) * 8;
  const u16* qbase = Qp + (size_t)(aa * 512) * 1024 + h * 64;

  float cs0 = 0.f, cs1 = 0.f, cs2 = 0.f, cs3 = 0.f;

  for (int q0 = 0; q0 < 512; q0 += 64) {
    __syncthreads();   // previous tile's reads complete
#pragma unroll
    for (int j = 0; j < 2; j++) {
      const int mi_ = wave * 2 + j;           // instr index 0..7
      const int row = q0 + mi_ * 8 + srow;
      glds16(qbase + (size_t)row * 1024 + scol, &qs[mi_ * 512 + lane * 8]);
    }
    __syncthreads();   // vmcnt drained: q-tile ready
#pragma unroll
    for (int qt = 0; qt < 4; qt++) {
      const int rbase = (qt * 16 + l15) * 64;
      const int sw = l15 & 7;
      short8 alo = *(const short8*)&qs[rbase + (quad ^ sw) * 8];
      short8 ahi = *(const short8*)&qs[rbase + ((4 + quad) ^ sw) * 8];
      f32x4 ac0 = (f32x4){0.f, 0.f, 0.f, 0.f};
      f32x4 ac1 = ac0, ac2 = ac0, ac3 = ac0;
      ac0 = __builtin_amdgcn_mfma_f32_16x16x32_bf16(alo, klo[0], ac0, 0, 0, 0);
      ac0 = __builtin_amdgcn_mfma_f32_16x16x32_bf16(ahi, khi[0], ac0, 0, 0, 0);
      ac1 = __builtin_amdgcn_mfma_f32_16x16x32_bf16(alo, klo[1], ac1, 0, 0, 0);
      ac1 = __builtin_amdgcn_mfma_f32_16x16x32_bf16(ahi, khi[1], ac1, 0, 0, 0);
      ac2 = __builtin_amdgcn_mfma_f32_16x16x32_bf16(alo, klo[2], ac2, 0, 0, 0);
      ac2 = __builtin_amdgcn_mfma_f32_16x16x32_bf16(ahi, khi[2], ac2, 0, 0, 0);
      ac3 = __builtin_amdgcn_mfma_f32_16x16x32_bf16(alo, klo[3], ac3, 0, 0, 0);
      ac3 = __builtin_amdgcn_mfma_f32_16x16x32_bf16(ahi, khi[3], ac3, 0, 0, 0);
#pragma unroll
      for (int r = 0; r < 4; r++) {
        cs0 += exp2f(ac0[r]);
        cs1 += exp2f(ac1[r]);
        cs2 += exp2f(ac2[r]);
        cs3 += exp2f(ac3[r]);
      }
    }
  }
  // finish column sums over the 4 quads
  cs0 += __shfl_xor(cs0, 16); cs0 += __shfl_xor(cs0, 32);
  cs1 += __shfl_xor(cs1, 16); cs1 += __shfl_xor(cs1, 32);
  cs2 += __shfl_xor(cs2, 16); cs2 += __shfl_xor(cs2, 32);
  cs3 += __shfl_xor(cs3, 16); cs3 += __shfl_xor(cs3, 32);
  const float v = quad == 0 ? cs0 : quad == 1 ? cs1 : quad == 2 ? cs2 : cs3;
  atomicAdd(out + (size_t)b * 8192 + h * 512 + kwave + quad * 16 + l15, __logf(v));
}

extern "C" void kernel_launch(void* const* d_in, const int* in_sizes, int n_in,
                              void* d_out, int out_size, void* d_ws, size_t ws_size,
                              hipStream_t stream) {
  const float* query  = (const float*)d_in[0];  // [8,512,1024]
  const float* memory = (const float*)d_in[1];  // [8,512,1024]
  const float* wq     = (const float*)d_in[2];  // [1024,1024]
  const float* wk     = (const float*)d_in[3];  // [1024,1024]
  float* out = (float*)d_out;                   // [8,16,512]

  char* ws = (char*)d_ws;
  const size_t MB = 1024 * 1024;
  u16* qb  = (u16*)(ws);             // 8 MB bf16 query
  u16* mb_ = (u16*)(ws + 8  * MB);   // 8 MB bf16 memory
  u16* wqb = (u16*)(ws + 16 * MB);   // 2 MB bf16 W_Q * c
  u16* wkb = (u16*)(ws + 18 * MB);   // 2 MB bf16 W_K
  u16* Qp  = (u16*)(ws + 20 * MB);   // 8 MB projected Q'
  u16* Kp  = (u16*)(ws + 28 * MB);   // 8 MB projected K

  prep<<<10304, 256, 0, stream>>>((const float4*)query, (const float4*)memory,
                                  (const float4*)wq, (const float4*)wk,
                                  (ushort4*)qb, (ushort4*)mb_, (ushort4*)wqb,
                                  (ushort4*)wkb, (float4*)d_out);
  gemm_bt2<<<dim3(8, 32, 2), 256, 0, stream>>>(qb, wqb, Qp, mb_, wkb, Kp);
  attn_lse2<<<dim3(16, 16, 8), 256, 0, stream>>>(Qp, Kp, out);
}

// Round 3
// 156.726 us; speedup vs baseline: 1.2487x; 1.1298x over previous
//
#include <hip/hip_runtime.h>
#include <hip/hip_bf16.h>

typedef short short8 __attribute__((ext_vector_type(8)));   // 8 bf16 = 4 VGPRs
typedef float f32x4 __attribute__((ext_vector_type(4)));
typedef unsigned short u16;

__device__ __forceinline__ unsigned short f2bf(float f) {
  unsigned int u = __float_as_uint(f);
  u += 0x7fffu + ((u >> 16) & 1u);    // round-to-nearest-even
  return (unsigned short)(u >> 16);
}

// async 16B global->LDS (dest = wave-uniform base + lane*16)
__device__ __forceinline__ void glds16(const void* g, void* l) {
  __builtin_amdgcn_global_load_lds(
      (const __attribute__((address_space(1))) unsigned int*)g,
      (__attribute__((address_space(3))) unsigned int*)l, 16, 0, 0);
}

// ---- fused: cast q/m -> bf16, cast wq*(1/(8 ln2)) -> bf16, cast wk, zero out ----
__global__ __launch_bounds__(256) void prep(const float4* __restrict__ q,
                                            const float4* __restrict__ m,
                                            const float4* __restrict__ wq,
                                            const float4* __restrict__ wk,
                                            ushort4* __restrict__ qb,
                                            ushort4* __restrict__ mb,
                                            ushort4* __restrict__ wqb,
                                            ushort4* __restrict__ wkb,
                                            float4* __restrict__ out0) {
  const int i = blockIdx.x * 256 + threadIdx.x;
  const float c = 0.18033688011112042f;  // 1/(8*ln2): folds SCALE and exp->exp2
  if (i < 1048576) {
    float4 v = q[i];
    ushort4 o; o.x = f2bf(v.x); o.y = f2bf(v.y); o.z = f2bf(v.z); o.w = f2bf(v.w);
    qb[i] = o;
  } else if (i < 2097152) {
    float4 v = m[i - 1048576];
    ushort4 o; o.x = f2bf(v.x); o.y = f2bf(v.y); o.z = f2bf(v.z); o.w = f2bf(v.w);
    mb[i - 1048576] = o;
  } else if (i < 2359296) {
    float4 v = wq[i - 2097152];
    ushort4 o; o.x = f2bf(v.x * c); o.y = f2bf(v.y * c); o.z = f2bf(v.z * c); o.w = f2bf(v.w * c);
    wqb[i - 2097152] = o;
  } else if (i < 2621440) {
    float4 v = wk[i - 2359296];
    ushort4 o; o.x = f2bf(v.x); o.y = f2bf(v.y); o.z = f2bf(v.z); o.w = f2bf(v.w);
    wkb[i - 2359296] = o;
  } else if (i < 2637824) {
    out0[i - 2621440] = (float4){0.f, 0.f, 0.f, 0.f};  // zero 65536-float output
  }
}

// ---- C[M,N] = A[M,1024] @ B[N,1024]^T, bf16, 64x128 tile (4 blocks/CU) ----
// z=0: Q-proj, z=1: K-proj. LDS xor-swizzle: chunk' = chunk ^ (row&7).
__global__ __launch_bounds__(256) void gemm_bt2(const u16* __restrict__ A0,
                                                const u16* __restrict__ B0,
                                                u16* __restrict__ C0,
                                                const u16* __restrict__ A1,
                                                const u16* __restrict__ B1,
                                                u16* __restrict__ C1) {
  __shared__ u16 As[64 * 64];    // 8 KB
  __shared__ u16 Bs[128 * 64];   // 16 KB
  const u16* A = blockIdx.z ? A1 : A0;
  const u16* B = blockIdx.z ? B1 : B0;
  u16* C = blockIdx.z ? C1 : C0;
  const int t = threadIdx.x;
  const int lane = t & 63, wave = t >> 6;
  const int l15 = lane & 15, quad = lane >> 4;
  const int mb = blockIdx.y * 64, nb = blockIdx.x * 128;
  const int wm = (wave & 1) * 32, wn = (wave >> 1) * 64;

  const int srow = lane >> 3;                 // 0..7 row within 8-row instr group
  const int scol = ((lane & 7) ^ srow) * 8;   // swizzled source column

  f32x4 acc[2][4];
#pragma unroll
  for (int i = 0; i < 2; i++)
#pragma unroll
    for (int j = 0; j < 4; j++) acc[i][j] = (f32x4){0.f, 0.f, 0.f, 0.f};

  for (int kb = 0; kb < 1024; kb += 64) {
#pragma unroll
    for (int j = 0; j < 2; j++) {             // As: 8 groups of 8 rows
      const int mi_ = wave * 2 + j;
      glds16(A + (size_t)(mb + mi_ * 8 + srow) * 1024 + kb + scol,
             &As[mi_ * 512 + lane * 8]);
    }
#pragma unroll
    for (int j = 0; j < 4; j++) {             // Bs: 16 groups of 8 rows
      const int mi_ = wave * 4 + j;
      glds16(B + (size_t)(nb + mi_ * 8 + srow) * 1024 + kb + scol,
             &Bs[mi_ * 512 + lane * 8]);
    }
    __syncthreads();   // drains vmcnt(0): LDS tiles ready
#pragma unroll
    for (int kk = 0; kk < 2; kk++) {
      const int cb = kk * 4;
      const int sw = l15 & 7;
      short8 af[2], bfr[4];
#pragma unroll
      for (int mi = 0; mi < 2; mi++)
        af[mi] = *(const short8*)&As[(wm + mi * 16 + l15) * 64 + ((cb + quad) ^ sw) * 8];
#pragma unroll
      for (int ni = 0; ni < 4; ni++)
        bfr[ni] = *(const short8*)&Bs[(wn + ni * 16 + l15) * 64 + ((cb + quad) ^ sw) * 8];
#pragma unroll
      for (int mi = 0; mi < 2; mi++)
#pragma unroll
        for (int ni = 0; ni < 4; ni++)
          acc[mi][ni] = __builtin_amdgcn_mfma_f32_16x16x32_bf16(
              af[mi], bfr[ni], acc[mi][ni], 0, 0, 0);
    }
    __syncthreads();   // all reads done before next iter's loads overwrite
  }
  // epilogue: C/D layout col=l15, row=quad*4+r
#pragma unroll
  for (int mi = 0; mi < 2; mi++)
#pragma unroll
    for (int r = 0; r < 4; r++) {
      const int row = mb + wm + mi * 16 + quad * 4 + r;
      const size_t base = (size_t)row * 1024 + nb + wn;
#pragma unroll
      for (int ni = 0; ni < 4; ni++)
        C[base + ni * 16 + l15] = f2bf(acc[mi][ni][r]);
    }
}

// ---- fused QK^T + columnwise LSE, a split across blocks, atomicAdd combine ----
// Each wave owns 64 k-columns (K-frags in regs). Q' pre-scaled by 1/(8 ln2):
// logit feeds raw v_exp_f32 (exp2). Double-buffered Q tile, 1 barrier/tile.
__global__ __launch_bounds__(256) void attn_lse2(const u16* __restrict__ Qp,
                                                 const u16* __restrict__ Kp,
                                                 float* __restrict__ out) {
  __shared__ u16 qs[2][64 * 64];   // 16 KB double-buffered
  const int t = threadIdx.x;
  const int lane = t & 63, wave = t >> 6;
  const int l15 = lane & 15, quad = lane >> 4;
  const int kt = blockIdx.x & 1, aa = blockIdx.x >> 1;
  const int h = blockIdx.y, b = blockIdx.z;
  const int kwave = kt * 256 + wave * 64;

  // K fragments for 4 k-tiles x (d-lo, d-hi), in registers throughout
  short8 klo[4], khi[4];
#pragma unroll
  for (int tt = 0; tt < 4; tt++) {
    const short8* kg = (const short8*)(Kp + (size_t)(b * 512 + kwave + tt * 16 + l15) * 1024
                                       + h * 64 + quad * 8);
    klo[tt] = kg[0];
    khi[tt] = kg[4];   // +32 elements
  }

  const int srow = lane >> 3;
  const int scol = ((lane & 7) ^ srow) * 8;
  const u16* qbase = Qp + (size_t)(aa * 512) * 1024 + h * 64;

  // loop-invariant swizzled LDS read columns (in u16 elements)
  const int sw = l15 & 7;
  const int colLo = (quad ^ sw) * 8;
  const int colHi = ((4 + quad) ^ sw) * 8;
  const int rrow = l15 * 64;   // qt adds a compile-time 16*64 stride

  float cs0 = 0.f, cs1 = 0.f, cs2 = 0.f, cs3 = 0.f;

  // prologue: stage tile 0
#pragma unroll
  for (int j = 0; j < 2; j++) {
    const int mi_ = wave * 2 + j;
    glds16(qbase + (size_t)(mi_ * 8 + srow) * 1024 + scol, &qs[0][mi_ * 512 + lane * 8]);
  }

  for (int i = 0; i < 8; i++) {
    __syncthreads();   // drains my tile-i loads; everyone done reading buf i^1
    if (i < 7) {
#pragma unroll
      for (int j = 0; j < 2; j++) {
        const int mi_ = wave * 2 + j;
        glds16(qbase + (size_t)((i + 1) * 64 + mi_ * 8 + srow) * 1024 + scol,
               &qs[(i + 1) & 1][mi_ * 512 + lane * 8]);
      }
    }
    const u16* buf = qs[i & 1];
#pragma unroll
    for (int qt = 0; qt < 4; qt++) {
      short8 alo = *(const short8*)&buf[qt * 1024 + rrow + colLo];
      short8 ahi = *(const short8*)&buf[qt * 1024 + rrow + colHi];
      f32x4 ac0 = (f32x4){0.f, 0.f, 0.f, 0.f};
      f32x4 ac1 = ac0, ac2 = ac0, ac3 = ac0;
      ac0 = __builtin_amdgcn_mfma_f32_16x16x32_bf16(alo, klo[0], ac0, 0, 0, 0);
      ac0 = __builtin_amdgcn_mfma_f32_16x16x32_bf16(ahi, khi[0], ac0, 0, 0, 0);
      ac1 = __builtin_amdgcn_mfma_f32_16x16x32_bf16(alo, klo[1], ac1, 0, 0, 0);
      ac1 = __builtin_amdgcn_mfma_f32_16x16x32_bf16(ahi, khi[1], ac1, 0, 0, 0);
      ac2 = __builtin_amdgcn_mfma_f32_16x16x32_bf16(alo, klo[2], ac2, 0, 0, 0);
      ac2 = __builtin_amdgcn_mfma_f32_16x16x32_bf16(ahi, khi[2], ac2, 0, 0, 0);
      ac3 = __builtin_amdgcn_mfma_f32_16x16x32_bf16(alo, klo[3], ac3, 0, 0, 0);
      ac3 = __builtin_amdgcn_mfma_f32_16x16x32_bf16(ahi, khi[3], ac3, 0, 0, 0);
#pragma unroll
      for (int r = 0; r < 4; r++) {
        cs0 += __builtin_amdgcn_exp2f(ac0[r]);   // bare v_exp_f32
        cs1 += __builtin_amdgcn_exp2f(ac1[r]);
        cs2 += __builtin_amdgcn_exp2f(ac2[r]);
        cs3 += __builtin_amdgcn_exp2f(ac3[r]);
      }
    }
  }
  // finish column sums over the 4 quads
  cs0 += __shfl_xor(cs0, 16); cs0 += __shfl_xor(cs0, 32);
  cs1 += __shfl_xor(cs1, 16); cs1 += __shfl_xor(cs1, 32);
  cs2 += __shfl_xor(cs2, 16); cs2 += __shfl_xor(cs2, 32);
  cs3 += __shfl_xor(cs3, 16); cs3 += __shfl_xor(cs3, 32);
  const float v = quad == 0 ? cs0 : quad == 1 ? cs1 : quad == 2 ? cs2 : cs3;
  atomicAdd(out + (size_t)b * 8192 + h * 512 + kwave + quad * 16 + l15, __logf(v));
}

extern "C" void kernel_launch(void* const* d_in, const int* in_sizes, int n_in,
                              void* d_out, int out_size, void* d_ws, size_t ws_size,
                              hipStream_t stream) {
  const float* query  = (const float*)d_in[0];  // [8,512,1024]
  const float* memory = (const float*)d_in[1];  // [8,512,1024]
  const float* wq     = (const float*)d_in[2];  // [1024,1024]
  const float* wk     = (const float*)d_in[3];  // [1024,1024]
  float* out = (float*)d_out;                   // [8,16,512]

  char* ws = (char*)d_ws;
  const size_t MB = 1024 * 1024;
  u16* qb  = (u16*)(ws);             // 8 MB bf16 query
  u16* mb_ = (u16*)(ws + 8  * MB);   // 8 MB bf16 memory
  u16* wqb = (u16*)(ws + 16 * MB);   // 2 MB bf16 W_Q * c
  u16* wkb = (u16*)(ws + 18 * MB);   // 2 MB bf16 W_K
  u16* Qp  = (u16*)(ws + 20 * MB);   // 8 MB projected Q'
  u16* Kp  = (u16*)(ws + 28 * MB);   // 8 MB projected K

  prep<<<10304, 256, 0, stream>>>((const float4*)query, (const float4*)memory,
                                  (const float4*)wq, (const float4*)wk,
                                  (ushort4*)qb, (ushort4*)mb_, (ushort4*)wqb,
                                  (ushort4*)wkb, (float4*)d_out);
  gemm_bt2<<<dim3(8, 64, 2), 256, 0, stream>>>(qb, wqb, Qp, mb_, wkb, Kp);
  attn_lse2<<<dim3(16, 16, 8), 256, 0, stream>>>(Qp, Kp, out);
}